// Round 1
// baseline (899.998 us; speedup 1.0000x reference)
//
#include <hip/hip_runtime.h>
#include <cmath>
#include <cstring>
#include <complex>

#define HCH 32

// ---------------- CG tables (computed on host, passed by value) ----------------
struct CGT {
  float c000;      // CG[0,0,0]
  float c011[9];   // [b*3+c]
  float c101[9];   // [a*3+c]
  float c110[9];   // [a*3+b]  (c=0)
  float c111[27];  // [(a*3+b)*3+c]
  float c121[45];  // [(a*5+b)*3+c]
};

static double factd(int n){ double r=1.0; for(int i=2;i<=n;++i) r*=i; return r; }

static double cg1(int l1,int m1,int l2,int m2,int l3,int m3){
  if(m1+m2!=m3) return 0.0;
  double pref = std::sqrt((2*l3+1)*factd(l3+l1-l2)*factd(l3-l1+l2)*factd(l1+l2-l3)/factd(l1+l2+l3+1));
  pref *= std::sqrt(factd(l3+m3)*factd(l3-m3)*factd(l1-m1)*factd(l1+m1)*factd(l2-m2)*factd(l2+m2));
  double s=0.0;
  for(int k=0;k<=l1+l2-l3;++k){
    int d[6]={k, l1+l2-l3-k, l1-m1-k, l2+m2-k, l3-l2+m1+k, l3-l1-m2+k};
    bool neg=false; for(int i=0;i<6;i++) if(d[i]<0) neg=true;
    if(neg) continue;
    double prod=1.0; for(int i=0;i<6;i++) prod*=factd(d[i]);
    s += ((k&1)? -1.0:1.0)/prod;
  }
  return pref*s;
}

static void qmat(int l, std::complex<double> Q[5][5]){
  int n=2*l+1;
  for(int i=0;i<5;i++) for(int j=0;j<5;j++) Q[i][j]=0.0;
  (void)n;
  Q[l][l]=1.0;
  const double is2 = 1.0/std::sqrt(2.0);
  for(int m=1;m<=l;m++){
    double sgn = (m&1)? -1.0: 1.0;
    Q[l+m][l+m] = sgn*is2;
    Q[l+m][l-m] = is2;
    Q[l-m][l-m] = std::complex<double>(0.0, is2);
    Q[l-m][l+m] = std::complex<double>(0.0, -sgn*is2);
  }
}

static void real_cg(int l1,int l2,int l3, float* out){
  int n1=2*l1+1, n2=2*l2+1, n3=2*l3+1;
  double Cc[5][5][5];
  std::memset(Cc,0,sizeof Cc);
  for(int m1=-l1;m1<=l1;m1++) for(int m2=-l2;m2<=l2;m2++){
    int m3=m1+m2;
    if(m3>=-l3 && m3<=l3) Cc[m1+l1][m2+l2][m3+l3]=cg1(l1,m1,l2,m2,l3,m3);
  }
  std::complex<double> Q1[5][5],Q2[5][5],Q3[5][5];
  qmat(l1,Q1); qmat(l2,Q2); qmat(l3,Q3);
  std::complex<double> C[5][5][5];
  double maxre=0.0, maxim=0.0;
  for(int a=0;a<n1;a++) for(int b=0;b<n2;b++) for(int c=0;c<n3;c++){
    std::complex<double> s=0.0;
    for(int i=0;i<n1;i++) for(int j=0;j<n2;j++) for(int k=0;k<n3;k++){
      double cc=Cc[i][j][k];
      if(cc!=0.0) s += Q1[a][i]*Q2[b][j]*std::conj(Q3[c][k])*cc;
    }
    C[a][b][c]=s;
    maxre=std::max(maxre,std::fabs(s.real()));
    maxim=std::max(maxim,std::fabs(s.imag()));
  }
  bool flip = maxim>maxre;
  for(int a=0;a<n1;a++) for(int b=0;b<n2;b++) for(int c=0;c<n3;c++){
    std::complex<double> v=C[a][b][c];
    if(flip) v *= std::complex<double>(0.0,-1.0);
    out[(a*n2+b)*n3+c]=(float)v.real();
  }
}

static void build_cg(CGT* cg){
  float t000[1];  real_cg(0,0,0,t000); cg->c000=t000[0];
  real_cg(0,1,1,cg->c011);   // [(0*3+b)*3+c] = b*3+c
  real_cg(1,0,1,cg->c101);   // [(a*1+0)*3+c] = a*3+c
  real_cg(1,1,0,cg->c110);   // [(a*3+b)*1+0] = a*3+b
  real_cg(1,1,1,cg->c111);
  real_cg(1,2,1,cg->c121);
}

// ---------------- device helpers ----------------
__device__ __forceinline__ float sspf(float x){
  // softplus(x) - ln2
  return fmaxf(x,0.0f) + log1pf(expf(-fabsf(x))) - 0.69314718055994530942f;
}

__device__ __forceinline__ float edge_env(float d, float* emb){
#pragma unroll
  for(int k=0;k<10;k++){
    float t = d - (0.7f + (float)k*(1.0f/9.0f));
    emb[k] = expf(-t*t*50.0f);   // 1/(2*0.1^2) = 50
  }
  float u = d*(1.0f/1.5f);
  if(u >= 1.0f) return 0.0f;
  float u2=u*u, u3=u2*u, u6=u3*u3, u7=u6*u, u8=u7*u;
  return 1.0f - 28.0f*u6 + 48.0f*u7 - 21.0f*u8;
}

// ---------------- layer 1: x (N,1,1) -> acc (N,4,H) ----------------
__global__ void l1_kernel(const float* __restrict__ x, const int* __restrict__ ei,
                          const float* __restrict__ sh, const float* __restrict__ elen,
                          const float* __restrict__ W1, const float* __restrict__ b1,
                          float* __restrict__ acc, int E, CGT cg){
  int t = blockIdx.x*blockDim.x + threadIdx.x;
  int e = t >> 5, h = t & 31;
  if(e >= E) return;
  float emb[10];
  float ew = edge_env(elen[e], emb);
  int src = ei[e], dst = ei[E+e];
  float w0 = b1[h], w1v = b1[HCH+h];
#pragma unroll
  for(int k=0;k<10;k++){
    w0  += emb[k]*W1[k*64 + h];
    w1v += emb[k]*W1[k*64 + HCH + h];
  }
  float xs = x[src];
  const float* she = sh + (size_t)e*9;
  float s0=she[0], s1=she[1], s2=she[2], s3=she[3];
  float base = xs*ew;
  float* ad = acc + (size_t)dst*128;
  atomicAdd(&ad[h], cg.c000*base*s0*w0);
#pragma unroll
  for(int c=0;c<3;c++){
    float tc = cg.c011[0*3+c]*s1 + cg.c011[1*3+c]*s2 + cg.c011[2*3+c]*s3;
    atomicAdd(&ad[(1+c)*HCH + h], tc*base*w1v);
  }
}

// ---------------- norm_act in-place on (N,4,H) ----------------
__global__ void normact_kernel(float* __restrict__ buf, int N){
  int t = blockIdx.x*blockDim.x + threadIdx.x;
  int n = t >> 5, h = t & 31;
  if(n >= N) return;
  float* p = buf + (size_t)n*128;
  float s  = p[h];
  float v1 = p[HCH+h], v2 = p[2*HCH+h], v3 = p[3*HCH+h];
  float nm = sqrtf(v1*v1 + v2*v2 + v3*v3 + 1e-12f);
  float sc = sspf(nm)/nm;
  p[h]       = sspf(s);
  p[HCH+h]   = v1*sc;
  p[2*HCH+h] = v2*sc;
  p[3*HCH+h] = v3*sc;
}

// ---------------- layer 2: h (N,4,H) -> acc (N,4,H), 6 paths, channel-wise ----------------
__global__ void l2_kernel(const float* __restrict__ hin, const int* __restrict__ ei,
                          const float* __restrict__ sh, const float* __restrict__ elen,
                          const float* __restrict__ W2, const float* __restrict__ b2,
                          float* __restrict__ acc, int E, CGT cg){
  int t = blockIdx.x*blockDim.x + threadIdx.x;
  int e = t >> 5, h = t & 31;
  if(e >= E) return;
  float emb[10];
  float ew = edge_env(elen[e], emb);
  int src = ei[e], dst = ei[E+e];
  float w[6];
#pragma unroll
  for(int p=0;p<6;p++) w[p] = b2[p*HCH + h];
#pragma unroll
  for(int k=0;k<10;k++){
    float ek = emb[k];
    const float* Wr = W2 + k*192;
#pragma unroll
    for(int p=0;p<6;p++) w[p] += ek*Wr[p*HCH + h];
  }
  const float* hn = hin + (size_t)src*128;
  float x0 = hn[h];
  float xv[3] = { hn[HCH+h], hn[2*HCH+h], hn[3*HCH+h] };
  const float* she = sh + (size_t)e*9;
  float s0 = she[0];
  float sv[3]  = { she[1], she[2], she[3] };
  float s2v[5] = { she[4], she[5], she[6], she[7], she[8] };

  float m0 = 0.0f, m[3] = {0.0f,0.0f,0.0f};
  // p0: (0,0,0)
  m0 += cg.c000 * x0 * s0 * w[0];
  // p1: (0,1,1)
#pragma unroll
  for(int c=0;c<3;c++){
    float tc = cg.c011[0*3+c]*sv[0] + cg.c011[1*3+c]*sv[1] + cg.c011[2*3+c]*sv[2];
    m[c] += tc * x0 * w[1];
  }
  // p2: (1,0,1)
#pragma unroll
  for(int c=0;c<3;c++){
    float tc = cg.c101[0*3+c]*xv[0] + cg.c101[1*3+c]*xv[1] + cg.c101[2*3+c]*xv[2];
    m[c] += tc * s0 * w[2];
  }
  // p3: (1,1,0)
  {
    float tt=0.0f;
#pragma unroll
    for(int a=0;a<3;a++)
#pragma unroll
      for(int b=0;b<3;b++) tt += cg.c110[a*3+b]*xv[a]*sv[b];
    m0 += tt * w[3];
  }
  // p4: (1,1,1)
#pragma unroll
  for(int c=0;c<3;c++){
    float tt=0.0f;
#pragma unroll
    for(int a=0;a<3;a++)
#pragma unroll
      for(int b=0;b<3;b++) tt += cg.c111[(a*3+b)*3+c]*xv[a]*sv[b];
    m[c] += tt * w[4];
  }
  // p5: (1,2,1)
#pragma unroll
  for(int c=0;c<3;c++){
    float tt=0.0f;
#pragma unroll
    for(int a=0;a<3;a++)
#pragma unroll
      for(int b=0;b<5;b++) tt += cg.c121[(a*5+b)*3+c]*xv[a]*s2v[b];
    m[c] += tt * w[5];
  }
  float* ad = acc + (size_t)dst*128;
  atomicAdd(&ad[h], m0*ew);
#pragma unroll
  for(int c=0;c<3;c++) atomicAdd(&ad[(1+c)*HCH + h], m[c]*ew);
}

// ---------------- layer 3: h (N,4,H) -> acc (N,1,H), 2 paths, channel-wise ----------------
__global__ void l3_kernel(const float* __restrict__ hin, const int* __restrict__ ei,
                          const float* __restrict__ sh, const float* __restrict__ elen,
                          const float* __restrict__ W3, const float* __restrict__ b3,
                          float* __restrict__ acc, int E, CGT cg){
  int t = blockIdx.x*blockDim.x + threadIdx.x;
  int e = t >> 5, h = t & 31;
  if(e >= E) return;
  float emb[10];
  float ew = edge_env(elen[e], emb);
  int src = ei[e], dst = ei[E+e];
  float w0 = b3[h], w1v = b3[HCH+h];
#pragma unroll
  for(int k=0;k<10;k++){
    w0  += emb[k]*W3[k*64 + h];
    w1v += emb[k]*W3[k*64 + HCH + h];
  }
  const float* hn = hin + (size_t)src*128;
  float x0 = hn[h];
  float xv[3] = { hn[HCH+h], hn[2*HCH+h], hn[3*HCH+h] };
  const float* she = sh + (size_t)e*9;
  float s0 = she[0];
  float sv[3] = { she[1], she[2], she[3] };
  float m = cg.c000 * x0 * s0 * w0;
  float tt=0.0f;
#pragma unroll
  for(int a=0;a<3;a++)
#pragma unroll
    for(int b=0;b<3;b++) tt += cg.c110[a*3+b]*xv[a]*sv[b];
  m += tt * w1v;
  atomicAdd(&acc[(size_t)dst*HCH + h], m*ew);
}

// ---------------- silu + graph pooling ----------------
__global__ void pool_kernel(const float* __restrict__ acc, const int* __restrict__ batch,
                            float* __restrict__ g, int N){
  int t = blockIdx.x*blockDim.x + threadIdx.x;
  int n = t >> 5, h = t & 31;
  if(n >= N) return;
  float v = acc[(size_t)n*HCH + h];
  float si = v/(1.0f + expf(-v));
  atomicAdd(&g[(size_t)batch[n]*HCH + h], si);
}

// ---------------- head: (128,32) @ (32,8) + bias -> softmax ----------------
__global__ void head_kernel(const float* __restrict__ g, const float* __restrict__ Wo,
                            const float* __restrict__ bo, float* __restrict__ out){
  int gi = threadIdx.x;
  if(gi >= 128) return;
  float logit[8];
#pragma unroll
  for(int o=0;o<8;o++) logit[o] = bo[o];
  for(int hh=0; hh<HCH; hh++){
    float gv = g[gi*HCH + hh];
#pragma unroll
    for(int o=0;o<8;o++) logit[o] += gv*Wo[hh*8 + o];
  }
  float mx = logit[0];
#pragma unroll
  for(int o=1;o<8;o++) mx = fmaxf(mx, logit[o]);
  float ex[8]; float s=0.0f;
#pragma unroll
  for(int o=0;o<8;o++){ ex[o]=expf(logit[o]-mx); s+=ex[o]; }
  float inv = 1.0f/s;
#pragma unroll
  for(int o=0;o<8;o++) out[gi*8 + o] = ex[o]*inv;
}

extern "C" void kernel_launch(void* const* d_in, const int* in_sizes, int n_in,
                              void* d_out, int out_size, void* d_ws, size_t ws_size,
                              hipStream_t stream){
  const float* x    = (const float*)d_in[0];
  const int*   ei   = (const int*)  d_in[1];
  const float* sh   = (const float*)d_in[2];
  const float* elen = (const float*)d_in[3];
  const int*   batch= (const int*)  d_in[4];
  const float* W1   = (const float*)d_in[5];
  const float* b1   = (const float*)d_in[6];
  const float* W2   = (const float*)d_in[7];
  const float* b2   = (const float*)d_in[8];
  const float* W3   = (const float*)d_in[9];
  const float* b3   = (const float*)d_in[10];
  const float* Wo   = (const float*)d_in[11];
  const float* bo   = (const float*)d_in[12];
  int N = in_sizes[0];
  int E = in_sizes[3];

  CGT cg; build_cg(&cg);

  float* bufA = (float*)d_ws;                      // N*128  (acc1 -> h1 in place)
  float* bufB = bufA + (size_t)N*128;              // N*128  (acc2 -> h2 in place)
  float* bufC = bufB + (size_t)N*128;              // N*32   (acc3)
  float* g    = bufC + (size_t)N*HCH;              // 128*32
  size_t zbytes = ((size_t)N*128*2 + (size_t)N*HCH + 128*HCH)*sizeof(float);
  hipMemsetAsync(d_ws, 0, zbytes, stream);

  dim3 blk(256);
  int eblocks = (int)(((long long)E*HCH + 255)/256);
  int nblocks = (int)(((long long)N*HCH + 255)/256);

  l1_kernel<<<eblocks, blk, 0, stream>>>(x, ei, sh, elen, W1, b1, bufA, E, cg);
  normact_kernel<<<nblocks, blk, 0, stream>>>(bufA, N);
  l2_kernel<<<eblocks, blk, 0, stream>>>(bufA, ei, sh, elen, W2, b2, bufB, E, cg);
  normact_kernel<<<nblocks, blk, 0, stream>>>(bufB, N);
  l3_kernel<<<eblocks, blk, 0, stream>>>(bufB, ei, sh, elen, W3, b3, bufC, E, cg);
  pool_kernel<<<nblocks, blk, 0, stream>>>(bufC, batch, g, N);
  head_kernel<<<1, 128, 0, stream>>>(g, Wo, bo, (float*)d_out);
}